// Round 5
// baseline (946.640 us; speedup 1.0000x reference)
//
#include <hip/hip_runtime.h>
#include <math.h>

typedef __attribute__((ext_vector_type(8))) short short8;
typedef __attribute__((ext_vector_type(4))) float float4v;
typedef __attribute__((ext_vector_type(4))) unsigned short ushort4v;

#define AST 136   // LDS activation row stride in bf16 (272 B, 16B-aligned)

__device__ __forceinline__ unsigned short f2bf(float f) {
    union { float f; unsigned u; } v; v.f = f;
    return (unsigned short)((v.u + 0x7fffu + ((v.u >> 16) & 1u)) >> 16);
}
__device__ __forceinline__ float bf2f(unsigned v) {
    union { unsigned u; float f; } x; x.u = v << 16; return x.f;
}

// ---------------------------------------------------------------------------
// Transposed-MFMA layer (wave-private, barrier-free):
//   D' = mfma(Wfrag, Actfrag)  ->  D'[i=out-feature][j=row]
//   A-op: lane(col0,q) holds WT[t*16+col0][k0..k0+7]   (global, L2-hot)
//   B-op: lane(col0,q) holds act[own row][k0..k0+7]    (LDS, own row)
//   C/D:  lane(col0,q) reg r -> row=col0, out-col=t*16+q*4+r (4 consecutive!)
// ---------------------------------------------------------------------------
template<int KP>
__device__ __forceinline__ void layerL(const unsigned short* hrow,
                                       const unsigned short* __restrict__ WT,
                                       const float* __restrict__ bias,
                                       int col0, int q, float4v acc[8])
{
#pragma unroll
    for (int t = 0; t < 8; ++t) {
        float4 bv = *(const float4*)(bias + t * 16 + q * 4);
        acc[t] = (float4v){bv.x, bv.y, bv.z, bv.w};
    }
#pragma unroll
    for (int ks = 0; ks < KP; ks += 32) {
        short8 Y = *(const short8*)(hrow + ks + q * 8);
#pragma unroll
        for (int t = 0; t < 8; ++t) {
            short8 B = *(const short8*)(WT + (size_t)(t * 16 + col0) * KP + ks + q * 8);
            acc[t] = __builtin_amdgcn_mfma_f32_16x16x32_bf16(B, Y, acc[t], 0, 0, 0);
        }
    }
}

// store transition: 8x ds_write_b64 into own row
__device__ __forceinline__ void storeT(float4v acc[8], unsigned short* hrow,
                                       int q, bool relu)
{
#pragma unroll
    for (int t = 0; t < 8; ++t) {
        ushort4v p;
#pragma unroll
        for (int r = 0; r < 4; ++r) {
            float v = acc[t][r];
            if (relu) v = fmaxf(v, 0.0f);
            p[r] = f2bf(v);
        }
        *(ushort4v*)(hrow + t * 16 + q * 4) = p;
    }
}

// ---------------------------------------------------------------------------
// weight prep: fp32 [K][128] -> bf16 transposed [128][KP] (zero k-padding)
// ---------------------------------------------------------------------------
__global__ void prep_kernel(const float* __restrict__ W_in, const float* __restrict__ W_g1,
                            const float* __restrict__ W_g2, const float* __restrict__ W_m1,
                            const float* __restrict__ W_m2, const float* __restrict__ W_out,
                            const float* __restrict__ W_attn, unsigned short* __restrict__ wt)
{
    int i = blockIdx.x * 256 + threadIdx.x;
    unsigned short* WT_in = wt;                 // [128][96]
    unsigned short* WT_g1 = WT_in + 12288;      // [128][128]
    unsigned short* WT_g2 = WT_g1 + 16384;      // [128][128]
    unsigned short* WT_m1 = WT_g2 + 16384;      // [128][416]
    unsigned short* WT_m2 = WT_m1 + 53248;      // [128][128]
    unsigned short* WT_h  = WT_m2 + 16384;      // [32][128]
    if (i < 12288) { int n = i / 96, k = i - n * 96;
        WT_in[i] = (k < 86) ? f2bf(W_in[k * 128 + n]) : 0; return; }
    i -= 12288;
    if (i < 16384) { int n = i >> 7, k = i & 127;
        WT_g1[i] = f2bf(W_g1[k * 128 + n]); return; }
    i -= 16384;
    if (i < 16384) { int n = i >> 7, k = i & 127;
        WT_g2[i] = f2bf(W_g2[k * 128 + n]); return; }
    i -= 16384;
    if (i < 53248) { int n = i / 416, k = i - n * 416;
        WT_m1[i] = (k < 397) ? f2bf(W_m1[k * 128 + n]) : 0; return; }
    i -= 53248;
    if (i < 16384) { int n = i >> 7, k = i & 127;
        WT_m2[i] = f2bf(W_m2[k * 128 + n]); return; }
    i -= 16384;
    if (i < 4096) { int n = i >> 7, k = i & 127;
        WT_h[i] = (n < 13) ? f2bf(W_out[k * 13 + n])
                           : (n < 26 ? f2bf(W_attn[k * 13 + (n - 13)]) : 0); }
}

// ---------------------------------------------------------------------------
// root encoder (fp32, tiny)
// ---------------------------------------------------------------------------
__global__ void root_kernel(const float* __restrict__ root_repr,
                            const float* __restrict__ W_root,
                            const float* __restrict__ b_root,
                            float* __restrict__ root_emb)
{
    __shared__ float x[86];
    const int r = blockIdx.x, tid = threadIdx.x;  // 128
    if (tid < 86) x[tid] = root_repr[(size_t)r * 86 + tid];
    __syncthreads();
    float acc = b_root[tid];
    for (int k = 0; k < 86; ++k)
        acc = fmaf(x[k], W_root[k * 128 + tid], acc);
    root_emb[(size_t)r * 128 + tid] = fmaxf(acc, 0.0f);
}

// ---------------------------------------------------------------------------
// node pipeline: block = 64 nodes, wave owns 16 rows x all 128 cols.
// Barrier-free 3-layer chain (wave-private LDS rows), then one barrier +
// 64-row segment scan (interior runs = stores, boundaries = atomics).
// ---------------------------------------------------------------------------
__global__ __launch_bounds__(256, 4)
void node_kernel(const float* __restrict__ node_h, const int* __restrict__ seg_ids,
                 const unsigned short* __restrict__ WT_in, const float* __restrict__ b_in,
                 const unsigned short* __restrict__ WT_g1, const float* __restrict__ b_g1,
                 const unsigned short* __restrict__ WT_g2, const float* __restrict__ b_g2,
                 float* __restrict__ frag_sum, float* __restrict__ frag_cnt)
{
    __shared__ __align__(16) unsigned short h[64 * AST];
    __shared__ int segs[64];
    const int tid = threadIdx.x, wv = tid >> 6, lane = tid & 63;
    const int col0 = lane & 15, q = lane >> 4;
    const int row = wv * 16 + col0;
    const long n0 = (long)blockIdx.x * 64;
    unsigned short* hrow = h + row * AST;

    if (tid < 64) segs[tid] = seg_ids[n0 + tid];

    const float* xrow = node_h + (n0 + row) * 86;
    float4v acc[8];
    // layer 1: K=96 (86 + pad), Y straight from global, NO relu
    {
#pragma unroll
        for (int t = 0; t < 8; ++t) {
            float4 bv = *(const float4*)(b_in + t * 16 + q * 4);
            acc[t] = (float4v){bv.x, bv.y, bv.z, bv.w};
        }
#pragma unroll
        for (int ks = 0; ks < 96; ks += 32) {
            const int k0 = ks + q * 8;
            short8 Y;
#pragma unroll
            for (int i = 0; i < 8; ++i) {
                int k = k0 + i;
                float v = (k < 86) ? xrow[k] : 0.0f;
                Y[i] = (short)f2bf(v);
            }
#pragma unroll
            for (int t = 0; t < 8; ++t) {
                short8 B = *(const short8*)(WT_in + (size_t)(t * 16 + col0) * 96 + k0);
                acc[t] = __builtin_amdgcn_mfma_f32_16x16x32_bf16(B, Y, acc[t], 0, 0, 0);
            }
        }
    }
    storeT(acc, hrow, q, false);
    layerL<128>(hrow, WT_g1, b_g1, col0, q, acc);
    storeT(acc, hrow, q, true);
    layerL<128>(hrow, WT_g2, b_g2, col0, q, acc);
    storeT(acc, hrow, q, true);     // h3 in LDS
    __syncthreads();

    // segment scan: thread (col = tid&127, half = tid>>7) scans 32 rows
    {
        const int col = tid & 127, half = tid >> 7, r0 = half << 5;
        const int prevSeg = (half == 1) ? segs[31] : -1;
        const int nextSeg = (half == 0) ? segs[32] : -1;
        int cur = segs[r0], runStart = r0;
        float sum = 0.f, cnt = 0.f;
        for (int n = r0; n < r0 + 32; ++n) {
            int s = segs[n];
            if (s != cur) {
                bool bnd = (runStart == r0) && (half == 0 || prevSeg == cur);
                if (bnd) atomicAdd(&frag_sum[(size_t)cur * 128 + col], sum);
                else     frag_sum[(size_t)cur * 128 + col] = sum;
                if (col == 0) {
                    if (bnd) atomicAdd(&frag_cnt[cur], cnt);
                    else     frag_cnt[cur] = cnt;
                }
                sum = 0.f; cnt = 0.f; cur = s; runStart = n;
            }
            sum += bf2f((unsigned)h[n * AST + col]);
            cnt += 1.f;
        }
        bool bnd = ((runStart == r0) && (half == 0 || prevSeg == cur))
                   || (half == 1) || (nextSeg == cur);
        if (bnd) atomicAdd(&frag_sum[(size_t)cur * 128 + col], sum);
        else     frag_sum[(size_t)cur * 128 + col] = sum;
        if (col == 0) {
            if (bnd) atomicAdd(&frag_cnt[cur], cnt);
            else     frag_cnt[cur] = cnt;
        }
    }
}

// ---------------------------------------------------------------------------
// fragment MLP + heads: block = 64 frags, wave owns 16; barrier-free.
// Layer m1's B-operand (cat, K=416) built on the fly from global.
// ---------------------------------------------------------------------------
__global__ __launch_bounds__(256, 3)
void frag_kernel(const float* __restrict__ root_emb, const float* __restrict__ frag_sum,
                 const float* __restrict__ frag_cnt, const int* __restrict__ ind_maps,
                 const int* __restrict__ broken,
                 const unsigned short* __restrict__ WT_m1, const float* __restrict__ b_m1,
                 const unsigned short* __restrict__ WT_m2, const float* __restrict__ b_m2,
                 const unsigned short* __restrict__ WT_h,
                 const float* __restrict__ b_out, const float* __restrict__ b_attn,
                 float* __restrict__ out0, float* __restrict__ out1)
{
    __shared__ __align__(16) unsigned short h[64 * AST];
    const int tid = threadIdx.x, wv = tid >> 6, lane = tid & 63;
    const int col0 = lane & 15, q = lane >> 4;
    const int row = wv * 16 + col0;
    const long f0 = (long)blockIdx.x * 64;
    unsigned short* hrow = h + row * AST;

    int fc = (int)(f0 + row); if (fc > 99999) fc = 99999;
    const int rid = ind_maps[fc];
    const float inv = 1.0f / fmaxf(frag_cnt[fc], 1.0f);
    int bi = broken[fc]; bi = bi < 0 ? 0 : (bi > 12 ? 12 : bi);

    float4v acc[8];
    // layer m1: K=416 (397 + pad)
    {
#pragma unroll
        for (int t = 0; t < 8; ++t) {
            float4 bv = *(const float4*)(b_m1 + t * 16 + q * 4);
            acc[t] = (float4v){bv.x, bv.y, bv.z, bv.w};
        }
#pragma unroll
        for (int ks = 0; ks < 416; ks += 32) {
            const int k0 = ks + q * 8;
            float av[8];
            if (ks >= 384) {
#pragma unroll
                for (int i = 0; i < 8; ++i) {
                    int oh = k0 + i - 384;
                    av[i] = (oh == bi) ? 1.0f : 0.0f;   // oh<13 always when ==bi
                }
            } else if (ks < 128) {
                const float4* e = (const float4*)(root_emb + (size_t)rid * 128 + k0);
                float4 e0 = e[0], e1 = e[1];
                av[0] = e0.x; av[1] = e0.y; av[2] = e0.z; av[3] = e0.w;
                av[4] = e1.x; av[5] = e1.y; av[6] = e1.z; av[7] = e1.w;
            } else if (ks < 256) {
                int kk = k0 - 128;
                const float4* e = (const float4*)(root_emb + (size_t)rid * 128 + kk);
                const float4* s = (const float4*)(frag_sum + (size_t)fc * 128 + kk);
                float4 e0 = e[0], e1 = e[1], s0 = s[0], s1 = s[1];
                av[0] = e0.x - s0.x * inv; av[1] = e0.y - s0.y * inv;
                av[2] = e0.z - s0.z * inv; av[3] = e0.w - s0.w * inv;
                av[4] = e1.x - s1.x * inv; av[5] = e1.y - s1.y * inv;
                av[6] = e1.z - s1.z * inv; av[7] = e1.w - s1.w * inv;
            } else {
                int kk = k0 - 256;
                const float4* s = (const float4*)(frag_sum + (size_t)fc * 128 + kk);
                float4 s0 = s[0], s1 = s[1];
                av[0] = s0.x * inv; av[1] = s0.y * inv; av[2] = s0.z * inv; av[3] = s0.w * inv;
                av[4] = s1.x * inv; av[5] = s1.y * inv; av[6] = s1.z * inv; av[7] = s1.w * inv;
            }
            short8 Y;
#pragma unroll
            for (int i = 0; i < 8; ++i) Y[i] = (short)f2bf(av[i]);
#pragma unroll
            for (int t = 0; t < 8; ++t) {
                short8 B = *(const short8*)(WT_m1 + (size_t)(t * 16 + col0) * 416 + k0);
                acc[t] = __builtin_amdgcn_mfma_f32_16x16x32_bf16(B, Y, acc[t], 0, 0, 0);
            }
        }
    }
    storeT(acc, hrow, q, true);     // h1
    layerL<128>(hrow, WT_m2, b_m2, col0, q, acc);
    storeT(acc, hrow, q, true);     // h2

    // heads: 2 n-tiles (26 valid), K=128, wave-private
    float4v hacc[2];
#pragma unroll
    for (int t = 0; t < 2; ++t) {
#pragma unroll
        for (int r = 0; r < 4; ++r) {
            int cc = t * 16 + q * 4 + r;
            hacc[t][r] = cc < 13 ? b_out[cc] : (cc < 26 ? b_attn[cc - 13] : 0.0f);
        }
    }
#pragma unroll
    for (int ks = 0; ks < 128; ks += 32) {
        const int k0 = ks + q * 8;
        short8 Y = *(const short8*)(hrow + k0);
#pragma unroll
        for (int t = 0; t < 2; ++t) {
            short8 B = *(const short8*)(WT_h + (size_t)(t * 16 + col0) * 128 + k0);
            hacc[t] = __builtin_amdgcn_mfma_f32_16x16x32_bf16(B, Y, hacc[t], 0, 0, 0);
        }
    }
    const long ff = f0 + row;
    if (ff < 100000) {
#pragma unroll
        for (int t = 0; t < 2; ++t)
#pragma unroll
            for (int r = 0; r < 4; ++r) {
                int cc = t * 16 + q * 4 + r;
                float v = hacc[t][r];
                if (cc < 13)      out0[ff * 13 + cc] = 1.0f / (1.0f + expf(-v));
                else if (cc < 26) out1[ff * 13 + cc - 13] = v;
            }
    }
}

extern "C" void kernel_launch(void* const* d_in, const int* in_sizes, int n_in,
                              void* d_out, int out_size, void* d_ws, size_t ws_size,
                              hipStream_t stream)
{
    const float* node_h    = (const float*)d_in[0];
    const int*   seg_ids   = (const int*)d_in[1];
    const float* root_repr = (const float*)d_in[2];
    const int*   ind_maps  = (const int*)d_in[3];
    const int*   broken    = (const int*)d_in[4];
    const float* W_root = (const float*)d_in[5];  const float* b_root = (const float*)d_in[6];
    const float* W_in   = (const float*)d_in[7];  const float* b_in   = (const float*)d_in[8];
    const float* W_g1   = (const float*)d_in[9];  const float* b_g1   = (const float*)d_in[10];
    const float* W_g2   = (const float*)d_in[11]; const float* b_g2   = (const float*)d_in[12];
    const float* W_m1   = (const float*)d_in[13]; const float* b_m1   = (const float*)d_in[14];
    const float* W_m2   = (const float*)d_in[15]; const float* b_m2   = (const float*)d_in[16];
    const float* W_out  = (const float*)d_in[17]; const float* b_out  = (const float*)d_in[18];
    const float* W_attn = (const float*)d_in[19]; const float* b_attn = (const float*)d_in[20];

    char* ws = (char*)d_ws;
    float* root_emb = (float*)ws;                          // 2000*128*4
    float* frag_sum = (float*)(ws + 1024000);              // 100000*128*4
    float* frag_cnt = (float*)(ws + 52224000);             // 100000*4
    unsigned short* wt = (unsigned short*)(ws + 52624000); // bf16 weights
    const unsigned short* WT_in = wt;
    const unsigned short* WT_g1 = wt + 12288;
    const unsigned short* WT_g2 = WT_g1 + 16384;
    const unsigned short* WT_m1 = WT_g2 + 16384;
    const unsigned short* WT_m2 = WT_m1 + 53248;
    const unsigned short* WT_h  = WT_m2 + 16384;

    hipMemsetAsync(frag_sum, 0, 51600000, stream);  // frag_sum + frag_cnt

    float* out0 = (float*)d_out;
    float* out1 = out0 + (size_t)100000 * 13;

    prep_kernel<<<464, 256, 0, stream>>>(W_in, W_g1, W_g2, W_m1, W_m2, W_out, W_attn, wt);
    root_kernel<<<2000, 128, 0, stream>>>(root_repr, W_root, b_root, root_emb);
    node_kernel<<<12500, 256, 0, stream>>>(node_h, seg_ids, WT_in, b_in,
                                           WT_g1, b_g1, WT_g2, b_g2, frag_sum, frag_cnt);
    frag_kernel<<<1563, 256, 0, stream>>>(root_emb, frag_sum, frag_cnt, ind_maps, broken,
                                          WT_m1, b_m1, WT_m2, b_m2, WT_h, b_out, b_attn,
                                          out0, out1);
}